// Round 7
// baseline (684.029 us; speedup 1.0000x reference)
//
#include <hip/hip_runtime.h>
#include <math.h>

#define NTOK 1024
#define EDIM 512
#define KVCH 1536
#define TKV  3072
#define VSTRIDE 6144

typedef __bf16 bf16x8 __attribute__((ext_vector_type(8)));
typedef float f32x4 __attribute__((ext_vector_type(4)));
#define MFMA16(a,b,c) __builtin_amdgcn_mfma_f32_16x16x32_bf16(a,b,c,0,0,0)

__device__ __forceinline__ ushort f2bf(float f){
    uint u = __float_as_uint(f);
    u += 0x7FFFu + ((u>>16)&1u);
    return (ushort)(u>>16);
}
__device__ __forceinline__ float bf2f(ushort h){ return __uint_as_float(((uint)h)<<16); }
__device__ __forceinline__ bf16x8 ldsb8(const ushort* p){ return *(const bf16x8*)p; }

// async global->LDS, 16B per lane. g is PER-LANE, l must be WAVE-UNIFORM base.
__device__ __forceinline__ void async16(const ushort* g, ushort* l){
    __builtin_amdgcn_global_load_lds((const __attribute__((address_space(1))) void*)g,
                                     (__attribute__((address_space(3))) void*)l, 16, 0, 0);
}

// ---------------- batched fp32 -> bf16 hi/lo split ----------------
#define NCVT 15
struct CvtJobs { const float* src[NCVT]; ushort* hi[NCVT]; ushort* lo[NCVT]; int n[NCVT]; };

__global__ __launch_bounds__(256) void cvt_hilo(CvtJobs J)
{
    int a = blockIdx.y;
    int i = (blockIdx.x*256 + threadIdx.x)*4;
    if (i >= J.n[a]) return;
    float4 v = *(const float4*)(J.src[a] + i);
    ushort4 h, l;
    h.x=f2bf(v.x); l.x=f2bf(v.x-bf2f(h.x));
    h.y=f2bf(v.y); l.y=f2bf(v.y-bf2f(h.y));
    h.z=f2bf(v.z); l.z=f2bf(v.z-bf2f(h.z));
    h.w=f2bf(v.w); l.w=f2bf(v.w-bf2f(h.w));
    *(ushort4*)(J.hi[a]+i) = h;
    *(ushort4*)(J.lo[a]+i) = l;
}

// ---------------- dual-descriptor MFMA GEMM: C = A @ B^T, bf16x3 split ----------------
// LDS per operand: combined hi|lo rows of 128B ([128 rows][8 granules of 16B]),
// granule position p holds source granule p^(r&7); g<4 -> hi col g*8, g>=4 -> lo col (g-4)*8.
struct GemmDesc {
    const ushort *Ahi, *Alo, *Bhi, *Blo;
    float* Cf; ushort *Chi, *Clo, *Cthi, *Ctlo;
    double* stats;                     // if set: atomicAdd {sum,sumsq} at stats[2*zb]
    int K, lda, ldb, ldc, ldct;
    int zmod;
    long sA0, sA1, sB0, sB1, sC0, sC1;
};

__device__ __forceinline__ void stage_ab(const ushort* hi, const ushort* lo, int ld, int k0,
                                         ushort* lds, int wave, int lane)
{
    #pragma unroll
    for (int i=0;i<4;++i){
        int r = (i<<5) + (wave<<3) + (lane>>3);
        int g = (lane&7) ^ (r&7);
        const ushort* s = ((g&4) ? lo : hi) + (size_t)r*ld + k0 + ((g&3)<<3);
        async16(s, lds + (((i<<5) + (wave<<3))<<6));
    }
}

__global__ __launch_bounds__(256) void mgemmF(GemmDesc D0, GemmDesc D1,
                                              int nblk0, int nx0, int ny0, int nx1, int ny1)
{
    __shared__ ushort A2[2][8192], B2[2][8192];
    __shared__ double sred[8];
    const int tid = threadIdx.x;
    int bid = blockIdx.x;
    GemmDesc d; int nx, ny, rel;
    if (bid < nblk0) { d = D0; rel = bid; nx = nx0; ny = ny0; }
    else             { d = D1; rel = bid - nblk0; nx = nx1; ny = ny1; }
    const int bx = rel % nx; int tt = rel / nx;
    const int by = tt % ny;  const int z = tt / ny;
    const int zb = z / d.zmod, zj = z - zb*d.zmod;
    const int mb = by<<7, nb = bx<<7;
    const ushort* Ah = d.Ahi + (size_t)zb*d.sA0 + (size_t)zj*d.sA1 + (size_t)mb*d.lda;
    const ushort* Al = d.Alo + (size_t)zb*d.sA0 + (size_t)zj*d.sA1 + (size_t)mb*d.lda;
    const ushort* Bh = d.Bhi + (size_t)zb*d.sB0 + (size_t)zj*d.sB1 + (size_t)nb*d.ldb;
    const ushort* Bl = d.Blo + (size_t)zb*d.sB0 + (size_t)zj*d.sB1 + (size_t)nb*d.ldb;
    const size_t coff = (size_t)zb*d.sC0 + (size_t)zj*d.sC1;
    const int wave = tid>>6, lane = tid&63;
    const int wr = wave>>1, wc = wave&1;
    const int fr = lane&15, fq = lane>>4;
    f32x4 acc[4][4];
    #pragma unroll
    for (int i=0;i<4;++i)
        #pragma unroll
        for (int j=0;j<4;++j) acc[i][j] = (f32x4){0.f,0.f,0.f,0.f};

    stage_ab(Ah, Al, d.lda, 0, A2[0], wave, lane);
    stage_ab(Bh, Bl, d.ldb, 0, B2[0], wave, lane);
    __syncthreads();
    int cur = 0;
    for (int k0=0; k0<d.K; k0+=32) {
        if (k0+32 < d.K) {
            stage_ab(Ah, Al, d.lda, k0+32, A2[cur^1], wave, lane);
            stage_ab(Bh, Bl, d.ldb, k0+32, B2[cur^1], wave, lane);
        }
        bf16x8 fah[4], fal[4];
        #pragma unroll
        for (int m=0;m<4;++m) {
            int r = wr*64 + m*16 + fr;
            const ushort* base = &A2[cur][r<<6];
            fah[m] = ldsb8(base + ((fq ^ (r&7))<<3));
            fal[m] = ldsb8(base + (((fq|4) ^ (r&7))<<3));
        }
        #pragma unroll
        for (int n=0;n<4;++n) {
            int r = wc*64 + n*16 + fr;
            const ushort* base = &B2[cur][r<<6];
            bf16x8 fbh = ldsb8(base + ((fq ^ (r&7))<<3));
            bf16x8 fbl = ldsb8(base + (((fq|4) ^ (r&7))<<3));
            #pragma unroll
            for (int m=0;m<4;++m) {
                acc[m][n] = MFMA16(fah[m], fbh, acc[m][n]);
                acc[m][n] = MFMA16(fah[m], fbl, acc[m][n]);
                acc[m][n] = MFMA16(fal[m], fbh, acc[m][n]);
            }
        }
        __syncthreads();
        cur ^= 1;
    }
    #pragma unroll
    for (int m=0;m<4;++m) {
        #pragma unroll
        for (int n=0;n<4;++n) {
            int row = mb + wr*64 + m*16 + fq*4;
            int col = nb + wc*64 + n*16 + fr;
            f32x4 v = acc[m][n];
            if (d.Cf) {
                #pragma unroll
                for (int r=0;r<4;++r) d.Cf[coff + (size_t)(row+r)*d.ldc + col] = v[r];
            }
            if (d.Chi) {
                #pragma unroll
                for (int r=0;r<4;++r) {
                    ushort hh = f2bf(v[r]);
                    size_t o = coff + (size_t)(row+r)*d.ldc + col;
                    d.Chi[o] = hh; d.Clo[o] = f2bf(v[r]-bf2f(hh));
                }
            }
            if (d.Cthi) {
                ushort4 h4, l4;
                #pragma unroll
                for (int r=0;r<4;++r) {
                    ushort hh = f2bf(v[r]);
                    ((ushort*)&h4)[r] = hh;
                    ((ushort*)&l4)[r] = f2bf(v[r]-bf2f(hh));
                }
                size_t o = coff + (size_t)col*d.ldct + row;
                *(ushort4*)(d.Cthi+o) = h4;
                *(ushort4*)(d.Ctlo+o) = l4;
            }
        }
    }
    if (d.stats) {
        double s=0.0, s2=0.0;
        #pragma unroll
        for (int m=0;m<4;++m)
            #pragma unroll
            for (int n=0;n<4;++n)
                #pragma unroll
                for (int r=0;r<4;++r) { double v = acc[m][n][r]; s += v; s2 += v*v; }
        #pragma unroll
        for (int off=32; off; off>>=1) { s += __shfl_xor(s, off); s2 += __shfl_xor(s2, off); }
        if (lane==0){ sred[wave]=s; sred[4+wave]=s2; }
        __syncthreads();
        if (tid==0) {
            atomicAdd(&d.stats[2*zb],   sred[0]+sred[1]+sred[2]+sred[3]);
            atomicAdd(&d.stats[2*zb+1], sred[4]+sred[5]+sred[6]+sred[7]);
        }
    }
}

// ---------------- channel softmax row-wise -> bf16 hi/lo ----------------
__global__ __launch_bounds__(256) void chan_softmax(const float* __restrict__ ATT, const double* __restrict__ ST,
                                                    ushort* __restrict__ Shi, ushort* __restrict__ Slo)
{
    int b = blockIdx.y;
    size_t ro = (size_t)b * KVCH * KVCH + (size_t)blockIdx.x * KVCH;
    const float* p = ATT + ro;
    ushort* ph = Shi + ro;
    ushort* pl = Slo + ro;
    double cnt = (double)KVCH * (double)KVCH;
    double mean = ST[2*b] / cnt;
    double var  = ST[2*b+1] / cnt - mean * mean;
    float sc = (float)(1.0 / sqrt(var + 1e-5));
    int tid = threadIdx.x;
    float x[6];
    #pragma unroll
    for (int k = 0; k < 6; ++k) x[k] = p[tid + (k << 8)] * sc;
    float mx = fmaxf(fmaxf(fmaxf(x[0],x[1]),fmaxf(x[2],x[3])),fmaxf(x[4],x[5]));
    #pragma unroll
    for (int m = 32; m; m >>= 1) mx = fmaxf(mx, __shfl_xor(mx, m));
    __shared__ float red[4];
    int w = tid >> 6;
    if ((tid & 63) == 0) red[w] = mx;
    __syncthreads();
    mx = fmaxf(fmaxf(red[0],red[1]), fmaxf(red[2],red[3]));
    __syncthreads();
    float e[6]; float sum = 0.f;
    #pragma unroll
    for (int k = 0; k < 6; ++k) { e[k] = __expf(x[k] - mx); sum += e[k]; }
    #pragma unroll
    for (int m = 32; m; m >>= 1) sum += __shfl_xor(sum, m);
    if ((tid & 63) == 0) red[w] = sum;
    __syncthreads();
    sum = red[0]+red[1]+red[2]+red[3];
    float inv = 1.0f / sum;
    #pragma unroll
    for (int k = 0; k < 6; ++k) {
        float pv = e[k] * inv;
        ushort hh = f2bf(pv);
        ph[tid + (k << 8)] = hh;
        pl[tid + (k << 8)] = f2bf(pv - bf2f(hh));
    }
}

// ---------------- merged per (b,h) 64x64 Gram + column sums (z=0: K, z=1..3: Q streams) ----------------
__global__ __launch_bounds__(256) void gram4(
    const ushort* __restrict__ Kbhi, const ushort* __restrict__ Kblo,
    const ushort* __restrict__ QBhi, const ushort* __restrict__ QBlo,
    float* __restrict__ GK, float* __restrict__ SK,
    float* __restrict__ GQ, float* __restrict__ SQm)
{
    int z = blockIdx.z;
    const ushort *Xh, *Xl; int T; float *G, *CS;
    if (z == 0) { Xh=Kbhi; Xl=Kblo; T=TKV; G=GK; CS=SK; }
    else { Xh=QBhi+(size_t)(z-1)*1048576; Xl=QBlo+(size_t)(z-1)*1048576;
           T=NTOK; G=GQ+(size_t)(z-1)*65536; CS=SQm+(size_t)(z-1)*1024; }
    int bh = blockIdx.x;
    int b = bh >> 3, h = bh & 7;
    const ushort* Xbh = Xh + (size_t)b * T * EDIM + h * 64;
    const ushort* Xbl = Xl + (size_t)b * T * EDIM + h * 64;
    int rows = T / gridDim.y;
    int t0 = blockIdx.y * rows;
    __shared__ float Xs[4][64];
    int tid = threadIdx.x;
    int i0 = (tid >> 4) << 2, j0 = (tid & 15) << 2;
    float acc[4][4] = {};
    float cs = 0.f;
    for (int t = t0; t < t0 + rows; t += 4) {
        __syncthreads();
        int r = tid >> 6, c = tid & 63;
        size_t gidx = (size_t)(t + r) * EDIM + c;
        Xs[r][c] = bf2f(Xbh[gidx]) + bf2f(Xbl[gidx]);
        __syncthreads();
        #pragma unroll
        for (int rr = 0; rr < 4; ++rr) {
            float xi0=Xs[rr][i0], xi1=Xs[rr][i0+1], xi2=Xs[rr][i0+2], xi3=Xs[rr][i0+3];
            float xj0=Xs[rr][j0], xj1=Xs[rr][j0+1], xj2=Xs[rr][j0+2], xj3=Xs[rr][j0+3];
            acc[0][0]=fmaf(xi0,xj0,acc[0][0]); acc[0][1]=fmaf(xi0,xj1,acc[0][1]); acc[0][2]=fmaf(xi0,xj2,acc[0][2]); acc[0][3]=fmaf(xi0,xj3,acc[0][3]);
            acc[1][0]=fmaf(xi1,xj0,acc[1][0]); acc[1][1]=fmaf(xi1,xj1,acc[1][1]); acc[1][2]=fmaf(xi1,xj2,acc[1][2]); acc[1][3]=fmaf(xi1,xj3,acc[1][3]);
            acc[2][0]=fmaf(xi2,xj0,acc[2][0]); acc[2][1]=fmaf(xi2,xj1,acc[2][1]); acc[2][2]=fmaf(xi2,xj2,acc[2][2]); acc[2][3]=fmaf(xi2,xj3,acc[2][3]);
            acc[3][0]=fmaf(xi3,xj0,acc[3][0]); acc[3][1]=fmaf(xi3,xj1,acc[3][1]); acc[3][2]=fmaf(xi3,xj2,acc[3][2]); acc[3][3]=fmaf(xi3,xj3,acc[3][3]);
        }
        if (tid < 64) cs += Xs[0][tid] + Xs[1][tid] + Xs[2][tid] + Xs[3][tid];
    }
    float* Gp = G + (size_t)bh * 4096;
    #pragma unroll
    for (int i = 0; i < 4; ++i)
        #pragma unroll
        for (int j = 0; j < 4; ++j)
            atomicAdd(&Gp[(i0 + i) * 64 + j0 + j], acc[i][j]);
    if (tid < 64) atomicAdd(&CS[bh * 64 + tid], cs);
}

// ---------------- per (st,b,h) scale = rsqrt(var(QK^T)+eps) ----------------
__global__ __launch_bounds__(256) void spatial_scale(
    const float* __restrict__ GQ, const float* __restrict__ GK,
    const float* __restrict__ SQm, const float* __restrict__ SKm, float* __restrict__ SVo)
{
    int st = blockIdx.y, bh = blockIdx.x, tid = threadIdx.x;
    const float* gq = GQ + (size_t)st*65536 + bh*4096;
    const float* gk = GK + bh*4096;
    double e2 = 0.0;
    for (int i = tid; i < 4096; i += 256)
        e2 += (double)gq[i] * (double)gk[i];
    double mm = 0.0;
    if (tid < 64) mm = (double)SQm[(size_t)st*1024 + bh*64 + tid] * (double)SKm[bh*64 + tid];
    #pragma unroll
    for (int m = 32; m; m >>= 1) { e2 += __shfl_xor(e2, m); mm += __shfl_xor(mm, m); }
    __shared__ double se[4], sm[4];
    int w = tid >> 6;
    if ((tid & 63) == 0) { se[w] = e2; sm[w] = mm; }
    __syncthreads();
    if (tid == 0) {
        double cnt = (double)NTOK * (double)TKV;
        double E2 = (se[0]+se[1]+se[2]+se[3]) / cnt;
        double M  = (sm[0]+sm[1]+sm[2]+sm[3]) / cnt;
        double var = E2 - M * M;
        SVo[st*16+bh] = (float)(1.0 / sqrt(var + 1e-5));
    }
}

// ---------------- MFMA flash attention: no-max softmax, bf16 P, double-buffered K/V ----------------
__global__ __launch_bounds__(256) void flash_mfma(
    const ushort* __restrict__ Qhi, const ushort* __restrict__ Qlo,
    const ushort* __restrict__ Khi, const ushort* __restrict__ Klo,
    const ushort* __restrict__ VThi, const ushort* __restrict__ VTlo,
    const float* __restrict__ SV,
    ushort* __restrict__ Ohi, ushort* __restrict__ Olo)
{
    __shared__ ushort Kh[2][4096], Kl[2][4096], Vh[2][4096], Vl[2][4096], Ph[4096];
    const int st = blockIdx.z, bh = blockIdx.y, b = bh>>3, h = bh&7;
    const int n0 = blockIdx.x<<6;
    const int tid = threadIdx.x, wave = tid>>6, lane = tid&63;
    const int fr = lane&15, fq = lane>>4;
    const float sc = SV[st*16 + bh];
    const size_t qb = (size_t)st*1048576 + (size_t)(b*1024 + n0)*512 + h*64;
    bf16x8 qfh[2], qfl[2];
    {
        const ushort* qph = Qhi + qb + (size_t)(wave*16 + fr)*512;
        const ushort* qpl = Qlo + qb + (size_t)(wave*16 + fr)*512;
        #pragma unroll
        for (int ks=0; ks<2; ++ks) {
            qfh[ks] = ldsb8(qph + ks*32 + fq*8);
            qfl[ks] = ldsb8(qpl + ks*32 + fq*8);
        }
    }
    f32x4 accO[4]; float lsum[4];
    #pragma unroll
    for (int i=0;i<4;++i){ accO[i]=(f32x4){0.f,0.f,0.f,0.f}; lsum[i]=0.f; }
    const size_t kb = (size_t)(b*TKV)*512 + h*64;
    const size_t vb = (size_t)(h*64)*VSTRIDE + b*TKV;

    auto stage_kv = [&](int tn, int buf){
        #pragma unroll
        for (int it=0; it<2; ++it) {
            int r  = (wave<<4) + (it<<3) + (lane>>3);
            int lb = ((wave<<4) + (it<<3)) << 6;
            int gck = ((lane&7) ^ (r&7)) << 3;
            size_t gk = kb + (size_t)(tn+r)*512 + gck;
            size_t gv = vb + (size_t)r*VSTRIDE + tn + gck;
            async16(Khi+gk, &Kh[buf][lb]);
            async16(Klo+gk, &Kl[buf][lb]);
            async16(VThi+gv, &Vh[buf][lb]);
            async16(VTlo+gv, &Vl[buf][lb]);
        }
    };

    stage_kv(0, 0);
    __syncthreads();
    int cur = 0;
    for (int t0=0; t0<TKV; t0+=64) {
        if (t0+64 < TKV) stage_kv(t0+64, cur^1);
        f32x4 s[4];
        #pragma unroll
        for (int i=0;i<4;++i) s[i]=(f32x4){0.f,0.f,0.f,0.f};
        #pragma unroll
        for (int ks=0; ks<2; ++ks) {
            #pragma unroll
            for (int nf=0; nf<4; ++nf) {
                int r = nf*16+fr;
                int ko = (r<<6) + ((ks*32 + fq*8) ^ ((r&7)<<3));
                bf16x8 kh = ldsb8(&Kh[cur][ko]), kl = ldsb8(&Kl[cur][ko]);
                s[nf] = MFMA16(qfh[ks], kh, s[nf]);
                s[nf] = MFMA16(qfh[ks], kl, s[nf]);
                s[nf] = MFMA16(qfl[ks], kh, s[nf]);
            }
        }
        #pragma unroll
        for (int reg=0; reg<4; ++reg) {
            int prow = fq*4+reg;
            float psum = 0.f;
            #pragma unroll
            for (int nf=0;nf<4;++nf){
                float p = __expf(sc * s[nf][reg]);
                psum += p;
                int pidx = (wave<<10) + (prow<<6) + ((nf*16+fr) ^ ((prow&7)<<3));
                Ph[pidx] = f2bf(p);
            }
            lsum[reg] += psum;
        }
        #pragma unroll
        for (int ks=0; ks<2; ++ks) {
            int po = (wave<<10) + (fr<<6) + ((ks*32 + fq*8) ^ ((fr&7)<<3));
            bf16x8 ph = ldsb8(&Ph[po]);
            #pragma unroll
            for (int df=0; df<4; ++df) {
                int dd = df*16+fr;
                int vo = (dd<<6) + ((ks*32 + fq*8) ^ ((dd&7)<<3));
                bf16x8 vh = ldsb8(&Vh[cur][vo]), vl = ldsb8(&Vl[cur][vo]);
                accO[df] = MFMA16(ph, vh, accO[df]);
                accO[df] = MFMA16(ph, vl, accO[df]);
            }
        }
        __syncthreads();
        cur ^= 1;
    }
    #pragma unroll
    for (int reg=0; reg<4; ++reg) {
        #pragma unroll
        for (int m=1; m<16; m<<=1) lsum[reg] += __shfl_xor(lsum[reg], m, 16);
        float inv = 1.f/lsum[reg];
        int row = n0 + wave*16 + fq*4 + reg;
        #pragma unroll
        for (int df=0; df<4; ++df) {
            float v = accO[df][reg]*inv;
            size_t o = (size_t)st*1048576 + (size_t)(b*1024+row)*512 + h*64 + df*16 + fr;
            ushort hh = f2bf(v);
            Ohi[o] = hh; Olo[o] = f2bf(v-bf2f(hh));
        }
    }
}

// ---------------- workspace layout (byte offsets) ----------------
constexpr size_t OFF_CH  = 0;           // 8 doubles
constexpr size_t OFF_GK  = 64;          // 65536 f32
constexpr size_t OFF_SK  = 262208;      // 1024 f32
constexpr size_t OFF_GQ  = 266304;      // 3*65536 f32
constexpr size_t OFF_SQM = 1052736;     // 3*1024 f32
constexpr size_t OFF_SV  = 1065024;     // 48 f32
constexpr size_t ZERO_BYTES = 1065024;
constexpr size_t S0 = 1065472;          // W8: 8 x 1 MB (hi 512KB + lo 512KB)
constexpr size_t S1 = S0 + 8388608;     // WC weights -> ATT f32 -> {QB hilo, Kb hilo}
constexpr size_t S2 = S1 + 28311552;    // embC hilo -> KVS hilo
constexpr size_t S3 = S2 + 12582912;    // emb123 hilo
constexpr size_t S4 = S3 + 12582912;    // QCt hilo -> SIMhi (spills into S5)
constexpr size_t S5 = S4 + 12582912;    // KCt hilo -> SIMlo tail -> CTX hilo
constexpr size_t S6 = S5 + 12582912;    // VC hilo -> VT hilo
// total = S6 + 12582912 = 100,680,192 bytes (~96 MB)

extern "C" void kernel_launch(void* const* d_in, const int* in_sizes, int n_in,
                              void* d_out, int out_size, void* d_ws, size_t ws_size,
                              hipStream_t stream)
{
    const float* emb[3] = {(const float*)d_in[0], (const float*)d_in[1], (const float*)d_in[2]};
    const float* embC = (const float*)d_in[3];
    const float* WqF[3] = {(const float*)d_in[4], (const float*)d_in[5], (const float*)d_in[6]};
    const float* WkF  = (const float*)d_in[7];
    const float* WvF  = (const float*)d_in[8];
    const float* WCF[3] = {(const float*)d_in[9], (const float*)d_in[10], (const float*)d_in[11]};
    const float* WoF[3] = {(const float*)d_in[12], (const float*)d_in[13], (const float*)d_in[14]};
    float* out = (float*)d_out;
    char* ws = (char*)d_ws;

    auto U16 = [&](size_t off)->ushort* { return (ushort*)(ws + off); };
    auto F32 = [&](size_t off)->float*  { return (float*)(ws + off); };

    double* CH = (double*)(ws + OFF_CH);
    float *GK = F32(OFF_GK), *SK = F32(OFF_SK), *GQ = F32(OFF_GQ), *SQm = F32(OFF_SQM), *SV = F32(OFF_SV);

    auto W8hi = [&](int i){ return U16(S0 + (size_t)i*1048576); };
    auto W8lo = [&](int i){ return U16(S0 + (size_t)i*1048576 + 524288); };
    auto WChi = [&](int i){ return U16(S1 + (size_t)i*9437184); };
    auto WClo = [&](int i){ return U16(S1 + (size_t)i*9437184 + 4718592); };
    ushort *embChi=U16(S2), *embClo=U16(S2+6291456);
    ushort *embhi=U16(S3), *emblo=U16(S3+6291456);
    ushort *QCthi=U16(S4), *QCtlo=U16(S4+6291456);
    ushort *KCthi=U16(S5), *KCtlo=U16(S5+6291456);
    ushort *VChi=U16(S6), *VClo=U16(S6+6291456);
    float  *ATT = F32(S1);
    ushort *SIMhi=U16(S4), *SIMlo=U16(S4+9437184);
    ushort *KVShi=U16(S2), *KVSlo=U16(S2+6291456);
    ushort *QBhi=U16(S1), *QBlo=U16(S1+6291456);
    ushort *Kbhi=U16(S1+12582912), *Kblo=U16(S1+12582912+6291456);
    ushort *VThi=U16(S6), *VTlo=U16(S6+6291456);
    ushort *CTXhi=U16(S5), *CTXlo=U16(S5+6291456);

    dim3 blk(256);
    (void)hipMemsetAsync(d_ws, 0, ZERO_BYTES, stream);

    // fp32 -> bf16 hi/lo conversions
    CvtJobs J;
    J.src[0]=embC;   J.hi[0]=embChi; J.lo[0]=embClo; J.n[0]=2048*KVCH;
    for (int s=0;s<3;++s){ J.src[1+s]=emb[s]; J.hi[1+s]=embhi+(size_t)s*1048576; J.lo[1+s]=emblo+(size_t)s*1048576; J.n[1+s]=2*NTOK*EDIM; }
    for (int s=0;s<3;++s){ J.src[4+s]=WqF[s]; J.hi[4+s]=W8hi(s); J.lo[4+s]=W8lo(s); J.n[4+s]=EDIM*EDIM; }
    J.src[7]=WkF; J.hi[7]=W8hi(3); J.lo[7]=W8lo(3); J.n[7]=EDIM*EDIM;
    J.src[8]=WvF; J.hi[8]=W8hi(4); J.lo[8]=W8lo(4); J.n[8]=EDIM*EDIM;
    for (int s=0;s<3;++s){ J.src[9+s]=WCF[s]; J.hi[9+s]=WChi(s); J.lo[9+s]=WClo(s); J.n[9+s]=KVCH*KVCH; }
    for (int s=0;s<3;++s){ J.src[12+s]=WoF[s]; J.hi[12+s]=W8hi(5+s); J.lo[12+s]=W8lo(5+s); J.n[12+s]=EDIM*EDIM; }
    cvt_hilo<<<dim3(3072, NCVT), blk, 0, stream>>>(J);

    GemmDesc Z{}; Z.zmod = 1;

    // L3: channel projections — QK transposed (z=w*2+b) + V natural (z=b)
    {
        GemmDesc dq = Z;
        dq.Ahi=embChi; dq.Alo=embClo; dq.Bhi=WChi(0); dq.Blo=WClo(0);
        dq.Cthi=QCthi; dq.Ctlo=QCtlo;
        dq.K=KVCH; dq.lda=KVCH; dq.ldb=KVCH; dq.ldct=NTOK;
        dq.zmod=2; dq.sA0=0; dq.sA1=(long)NTOK*KVCH; dq.sB0=4718592; dq.sB1=0;
        dq.sC0=6291456; dq.sC1=(long)KVCH*NTOK;
        GemmDesc dv = Z;
        dv.Ahi=embChi; dv.Alo=embClo; dv.Bhi=WChi(2); dv.Blo=WClo(2);
        dv.Chi=VChi; dv.Clo=VClo;
        dv.K=KVCH; dv.lda=KVCH; dv.ldb=KVCH; dv.ldc=KVCH;
        dv.sA0=(long)NTOK*KVCH; dv.sC0=(long)NTOK*KVCH;
        mgemmF<<<dim3(576), blk, 0, stream>>>(dq, dv, 384, 12, 8, 12, 8);
    }
    // L4: ATT[b] = QC^T KC (+ mean/var stats in epilogue)
    {
        GemmDesc da = Z;
        da.Ahi=QCthi; da.Alo=QCtlo; da.Bhi=KCthi; da.Blo=KCtlo;
        da.Cf=ATT; da.stats=CH;
        da.K=NTOK; da.lda=NTOK; da.ldb=NTOK; da.ldc=KVCH;
        da.sA0=(long)KVCH*NTOK; da.sB0=(long)KVCH*NTOK; da.sC0=(long)KVCH*KVCH;
        mgemmF<<<dim3(288), blk, 0, stream>>>(da, da, 288, 12, 12, 1, 1);
    }
    chan_softmax<<<dim3(1536,2), blk, 0, stream>>>(ATT, CH, SIMhi, SIMlo);
    // L6: KVS (z=b*3+j) + Q projections (z=stream)
    {
        GemmDesc dk = Z;
        dk.Ahi=VChi; dk.Alo=VClo; dk.Bhi=SIMhi; dk.Blo=SIMlo;
        dk.Chi=KVShi; dk.Clo=KVSlo;
        dk.K=KVCH; dk.lda=KVCH; dk.ldb=KVCH; dk.ldc=EDIM;
        dk.zmod=3; dk.sA0=(long)NTOK*KVCH; dk.sA1=0;
        dk.sB0=(long)KVCH*KVCH; dk.sB1=(long)EDIM*KVCH;
        dk.sC0=(long)TKV*EDIM; dk.sC1=(long)NTOK*EDIM;
        GemmDesc dqp = Z;
        dqp.Ahi=embhi; dqp.Alo=emblo; dqp.Bhi=W8hi(0); dqp.Blo=W8lo(0);
        dqp.Chi=QBhi; dqp.Clo=QBlo;
        dqp.K=EDIM; dqp.lda=EDIM; dqp.ldb=EDIM; dqp.ldc=EDIM;
        dqp.sA0=1048576; dqp.sB0=524288; dqp.sC0=1048576;
        mgemmF<<<dim3(384), blk, 0, stream>>>(dk, dqp, 192, 4, 8, 4, 16);
    }
    // L7: K projection (natural) + V projection (transposed -> VT directly)
    {
        GemmDesc dkp = Z;
        dkp.Ahi=KVShi; dkp.Alo=KVSlo; dkp.Bhi=W8hi(3); dkp.Blo=W8lo(3);
        dkp.Chi=Kbhi; dkp.Clo=Kblo;
        dkp.K=EDIM; dkp.lda=EDIM; dkp.ldb=EDIM; dkp.ldc=EDIM;
        GemmDesc dvp = Z;
        dvp.Ahi=KVShi; dvp.Alo=KVSlo; dvp.Bhi=W8hi(4); dvp.Blo=W8lo(4);
        dvp.Cthi=VThi; dvp.Ctlo=VTlo;
        dvp.K=EDIM; dvp.lda=EDIM; dvp.ldb=EDIM; dvp.ldct=VSTRIDE;
        mgemmF<<<dim3(384), blk, 0, stream>>>(dkp, dvp, 192, 4, 48, 4, 48);
    }
    gram4<<<dim3(16,8,4), blk, 0, stream>>>(Kbhi, Kblo, QBhi, QBlo, GK, SK, GQ, SQm);
    spatial_scale<<<dim3(16,3), blk, 0, stream>>>(GQ, GK, SQm, SK, SV);
    flash_mfma<<<dim3(16,16,3), blk, 0, stream>>>(QBhi, QBlo, Kbhi, Kblo, VThi, VTlo, SV, CTXhi, CTXlo);
    // L11: output projections
    {
        GemmDesc dop = Z;
        dop.Ahi=CTXhi; dop.Alo=CTXlo; dop.Bhi=W8hi(5); dop.Blo=W8lo(5);
        dop.Cf=out;
        dop.K=EDIM; dop.lda=EDIM; dop.ldb=EDIM; dop.ldc=EDIM;
        dop.sA0=1048576; dop.sB0=524288; dop.sC0=1048576;
        mgemmF<<<dim3(192), blk, 0, stream>>>(dop, dop, 192, 4, 16, 1, 1);
    }
}

// Round 8
// 639.375 us; speedup vs baseline: 1.0698x; 1.0698x over previous
//
#include <hip/hip_runtime.h>
#include <math.h>

#define NTOK 1024
#define EDIM 512
#define KVCH 1536
#define TKV  3072
#define VSTRIDE 6144

typedef __bf16 bf16x8 __attribute__((ext_vector_type(8)));
typedef float f32x4 __attribute__((ext_vector_type(4)));
#define MFMA16(a,b,c) __builtin_amdgcn_mfma_f32_16x16x32_bf16(a,b,c,0,0,0)

__device__ __forceinline__ ushort f2bf(float f){
    uint u = __float_as_uint(f);
    u += 0x7FFFu + ((u>>16)&1u);
    return (ushort)(u>>16);
}
__device__ __forceinline__ float bf2f(ushort h){ return __uint_as_float(((uint)h)<<16); }
__device__ __forceinline__ bf16x8 ldsb8(const ushort* p){ return *(const bf16x8*)p; }

// async global->LDS, 16B per lane. g is PER-LANE, l must be WAVE-UNIFORM base.
__device__ __forceinline__ void async16(const ushort* g, ushort* l){
    __builtin_amdgcn_global_load_lds((const __attribute__((address_space(1))) void*)g,
                                     (__attribute__((address_space(3))) void*)l, 16, 0, 0);
}

// ---------------- batched fp32 -> bf16 hi/lo split ----------------
#define NCVT 15
struct CvtJobs { const float* src[NCVT]; ushort* hi[NCVT]; ushort* lo[NCVT]; int n[NCVT]; };

__global__ __launch_bounds__(256) void cvt_hilo(CvtJobs J)
{
    int a = blockIdx.y;
    int i = (blockIdx.x*256 + threadIdx.x)*4;
    if (i >= J.n[a]) return;
    float4 v = *(const float4*)(J.src[a] + i);
    ushort4 h, l;
    h.x=f2bf(v.x); l.x=f2bf(v.x-bf2f(h.x));
    h.y=f2bf(v.y); l.y=f2bf(v.y-bf2f(h.y));
    h.z=f2bf(v.z); l.z=f2bf(v.z-bf2f(h.z));
    h.w=f2bf(v.w); l.w=f2bf(v.w-bf2f(h.w));
    *(ushort4*)(J.hi[a]+i) = h;
    *(ushort4*)(J.lo[a]+i) = l;
}

// ---------------- dual-descriptor MFMA GEMM: C = A @ B^T, bf16x3 split ----------------
// LDS per operand: combined hi|lo rows of 128B; granule p holds source granule p^(r&7).
struct GemmDesc {
    const ushort *Ahi, *Alo, *Bhi, *Blo;
    float* Cf; ushort *Chi, *Clo, *Cthi, *Ctlo;
    double* stats;                     // if set: atomicAdd {sum,sumsq} at stats[2*zb]
    int K, lda, ldb, ldc, ldct;
    int zmod;
    long sA0, sA1, sB0, sB1, sC0, sC1;
};

__device__ __forceinline__ void stage_ab(const ushort* hi, const ushort* lo, int ld, int k0,
                                         ushort* lds, int wave, int lane)
{
    #pragma unroll
    for (int i=0;i<4;++i){
        int r = (i<<5) + (wave<<3) + (lane>>3);
        int g = (lane&7) ^ (r&7);
        const ushort* s = ((g&4) ? lo : hi) + (size_t)r*ld + k0 + ((g&3)<<3);
        async16(s, lds + (((i<<5) + (wave<<3))<<6));
    }
}

__global__ __launch_bounds__(256) void mgemmF(GemmDesc D0, GemmDesc D1,
                                              int nblk0, int nx0, int ny0, int nx1, int ny1)
{
    __shared__ ushort A2[2][8192], B2[2][8192];
    __shared__ double sred[8];
    const int tid = threadIdx.x;
    int bid = blockIdx.x;
    GemmDesc d; int nx, ny, rel;
    if (bid < nblk0) { d = D0; rel = bid; nx = nx0; ny = ny0; }
    else             { d = D1; rel = bid - nblk0; nx = nx1; ny = ny1; }
    const int bx = rel % nx; int tt = rel / nx;
    const int by = tt % ny;  const int z = tt / ny;
    const int zb = z / d.zmod, zj = z - zb*d.zmod;
    const int mb = by<<7, nb = bx<<7;
    const ushort* Ah = d.Ahi + (size_t)zb*d.sA0 + (size_t)zj*d.sA1 + (size_t)mb*d.lda;
    const ushort* Al = d.Alo + (size_t)zb*d.sA0 + (size_t)zj*d.sA1 + (size_t)mb*d.lda;
    const ushort* Bh = d.Bhi + (size_t)zb*d.sB0 + (size_t)zj*d.sB1 + (size_t)nb*d.ldb;
    const ushort* Bl = d.Blo + (size_t)zb*d.sB0 + (size_t)zj*d.sB1 + (size_t)nb*d.ldb;
    const size_t coff = (size_t)zb*d.sC0 + (size_t)zj*d.sC1;
    const int wave = tid>>6, lane = tid&63;
    const int wr = wave>>1, wc = wave&1;
    const int fr = lane&15, fq = lane>>4;
    f32x4 acc[4][4];
    #pragma unroll
    for (int i=0;i<4;++i)
        #pragma unroll
        for (int j=0;j<4;++j) acc[i][j] = (f32x4){0.f,0.f,0.f,0.f};

    stage_ab(Ah, Al, d.lda, 0, A2[0], wave, lane);
    stage_ab(Bh, Bl, d.ldb, 0, B2[0], wave, lane);
    __syncthreads();
    int cur = 0;
    for (int k0=0; k0<d.K; k0+=32) {
        if (k0+32 < d.K) {
            stage_ab(Ah, Al, d.lda, k0+32, A2[cur^1], wave, lane);
            stage_ab(Bh, Bl, d.ldb, k0+32, B2[cur^1], wave, lane);
        }
        bf16x8 fah[4], fal[4];
        #pragma unroll
        for (int m=0;m<4;++m) {
            int r = wr*64 + m*16 + fr;
            const ushort* base = &A2[cur][r<<6];
            fah[m] = ldsb8(base + ((fq ^ (r&7))<<3));
            fal[m] = ldsb8(base + (((fq|4) ^ (r&7))<<3));
        }
        __builtin_amdgcn_s_setprio(1);
        #pragma unroll
        for (int n=0;n<4;++n) {
            int r = wc*64 + n*16 + fr;
            const ushort* base = &B2[cur][r<<6];
            bf16x8 fbh = ldsb8(base + ((fq ^ (r&7))<<3));
            bf16x8 fbl = ldsb8(base + (((fq|4) ^ (r&7))<<3));
            #pragma unroll
            for (int m=0;m<4;++m) {
                acc[m][n] = MFMA16(fah[m], fbh, acc[m][n]);
                acc[m][n] = MFMA16(fah[m], fbl, acc[m][n]);
                acc[m][n] = MFMA16(fal[m], fbh, acc[m][n]);
            }
        }
        __builtin_amdgcn_s_setprio(0);
        __syncthreads();
        cur ^= 1;
    }
    #pragma unroll
    for (int m=0;m<4;++m) {
        #pragma unroll
        for (int n=0;n<4;++n) {
            int row = mb + wr*64 + m*16 + fq*4;
            int col = nb + wc*64 + n*16 + fr;
            f32x4 v = acc[m][n];
            if (d.Cf) {
                #pragma unroll
                for (int r=0;r<4;++r) d.Cf[coff + (size_t)(row+r)*d.ldc + col] = v[r];
            }
            if (d.Chi) {
                #pragma unroll
                for (int r=0;r<4;++r) {
                    ushort hh = f2bf(v[r]);
                    size_t o = coff + (size_t)(row+r)*d.ldc + col;
                    d.Chi[o] = hh; d.Clo[o] = f2bf(v[r]-bf2f(hh));
                }
            }
            if (d.Cthi) {
                ushort4 h4, l4;
                #pragma unroll
                for (int r=0;r<4;++r) {
                    ushort hh = f2bf(v[r]);
                    ((ushort*)&h4)[r] = hh;
                    ((ushort*)&l4)[r] = f2bf(v[r]-bf2f(hh));
                }
                size_t o = coff + (size_t)col*d.ldct + row;
                *(ushort4*)(d.Cthi+o) = h4;
                *(ushort4*)(d.Ctlo+o) = l4;
            }
        }
    }
    if (d.stats) {
        double s=0.0, s2=0.0;
        #pragma unroll
        for (int m=0;m<4;++m)
            #pragma unroll
            for (int n=0;n<4;++n)
                #pragma unroll
                for (int r=0;r<4;++r) { double v = acc[m][n][r]; s += v; s2 += v*v; }
        #pragma unroll
        for (int off=32; off; off>>=1) { s += __shfl_xor(s, off); s2 += __shfl_xor(s2, off); }
        if (lane==0){ sred[wave]=s; sred[4+wave]=s2; }
        __syncthreads();
        if (tid==0) {
            atomicAdd(&d.stats[2*zb],   sred[0]+sred[1]+sred[2]+sred[3]);
            atomicAdd(&d.stats[2*zb+1], sred[4]+sred[5]+sred[6]+sred[7]);
        }
    }
}

// ---------------- channel softmax row-wise -> bf16 hi/lo ----------------
__global__ __launch_bounds__(256) void chan_softmax(const float* __restrict__ ATT, const double* __restrict__ ST,
                                                    ushort* __restrict__ Shi, ushort* __restrict__ Slo)
{
    int b = blockIdx.y;
    size_t ro = (size_t)b * KVCH * KVCH + (size_t)blockIdx.x * KVCH;
    const float* p = ATT + ro;
    ushort* ph = Shi + ro;
    ushort* pl = Slo + ro;
    double cnt = (double)KVCH * (double)KVCH;
    double mean = ST[2*b] / cnt;
    double var  = ST[2*b+1] / cnt - mean * mean;
    float sc = (float)(1.0 / sqrt(var + 1e-5));
    int tid = threadIdx.x;
    float x[6];
    #pragma unroll
    for (int k = 0; k < 6; ++k) x[k] = p[tid + (k << 8)] * sc;
    float mx = fmaxf(fmaxf(fmaxf(x[0],x[1]),fmaxf(x[2],x[3])),fmaxf(x[4],x[5]));
    #pragma unroll
    for (int m = 32; m; m >>= 1) mx = fmaxf(mx, __shfl_xor(mx, m));
    __shared__ float red[4];
    int w = tid >> 6;
    if ((tid & 63) == 0) red[w] = mx;
    __syncthreads();
    mx = fmaxf(fmaxf(red[0],red[1]), fmaxf(red[2],red[3]));
    __syncthreads();
    float e[6]; float sum = 0.f;
    #pragma unroll
    for (int k = 0; k < 6; ++k) { e[k] = __expf(x[k] - mx); sum += e[k]; }
    #pragma unroll
    for (int m = 32; m; m >>= 1) sum += __shfl_xor(sum, m);
    if ((tid & 63) == 0) red[w] = sum;
    __syncthreads();
    sum = red[0]+red[1]+red[2]+red[3];
    float inv = 1.0f / sum;
    #pragma unroll
    for (int k = 0; k < 6; ++k) {
        float pv = e[k] * inv;
        ushort hh = f2bf(pv);
        ph[tid + (k << 8)] = hh;
        pl[tid + (k << 8)] = f2bf(pv - bf2f(hh));
    }
}

// ---------------- merged per (b,h) 64x64 Gram + column sums (z=0: K, z=1..3: Q streams) ----------------
__global__ __launch_bounds__(256) void gram4(
    const ushort* __restrict__ Kbhi, const ushort* __restrict__ Kblo,
    const ushort* __restrict__ QBhi, const ushort* __restrict__ QBlo,
    float* __restrict__ GK, float* __restrict__ SK,
    float* __restrict__ GQ, float* __restrict__ SQm)
{
    int z = blockIdx.z;
    const ushort *Xh, *Xl; int T; float *G, *CS;
    if (z == 0) { Xh=Kbhi; Xl=Kblo; T=TKV; G=GK; CS=SK; }
    else { Xh=QBhi+(size_t)(z-1)*1048576; Xl=QBlo+(size_t)(z-1)*1048576;
           T=NTOK; G=GQ+(size_t)(z-1)*65536; CS=SQm+(size_t)(z-1)*1024; }
    int bh = blockIdx.x;
    int b = bh >> 3, h = bh & 7;
    const ushort* Xbh = Xh + (size_t)b * T * EDIM + h * 64;
    const ushort* Xbl = Xl + (size_t)b * T * EDIM + h * 64;
    int rows = T / gridDim.y;
    int t0 = blockIdx.y * rows;
    __shared__ float Xs[4][64];
    int tid = threadIdx.x;
    int i0 = (tid >> 4) << 2, j0 = (tid & 15) << 2;
    float acc[4][4] = {};
    float cs = 0.f;
    for (int t = t0; t < t0 + rows; t += 4) {
        __syncthreads();
        int r = tid >> 6, c = tid & 63;
        size_t gidx = (size_t)(t + r) * EDIM + c;
        Xs[r][c] = bf2f(Xbh[gidx]) + bf2f(Xbl[gidx]);
        __syncthreads();
        #pragma unroll
        for (int rr = 0; rr < 4; ++rr) {
            float xi0=Xs[rr][i0], xi1=Xs[rr][i0+1], xi2=Xs[rr][i0+2], xi3=Xs[rr][i0+3];
            float xj0=Xs[rr][j0], xj1=Xs[rr][j0+1], xj2=Xs[rr][j0+2], xj3=Xs[rr][j0+3];
            acc[0][0]=fmaf(xi0,xj0,acc[0][0]); acc[0][1]=fmaf(xi0,xj1,acc[0][1]); acc[0][2]=fmaf(xi0,xj2,acc[0][2]); acc[0][3]=fmaf(xi0,xj3,acc[0][3]);
            acc[1][0]=fmaf(xi1,xj0,acc[1][0]); acc[1][1]=fmaf(xi1,xj1,acc[1][1]); acc[1][2]=fmaf(xi1,xj2,acc[1][2]); acc[1][3]=fmaf(xi1,xj3,acc[1][3]);
            acc[2][0]=fmaf(xi2,xj0,acc[2][0]); acc[2][1]=fmaf(xi2,xj1,acc[2][1]); acc[2][2]=fmaf(xi2,xj2,acc[2][2]); acc[2][3]=fmaf(xi2,xj3,acc[2][3]);
            acc[3][0]=fmaf(xi3,xj0,acc[3][0]); acc[3][1]=fmaf(xi3,xj1,acc[3][1]); acc[3][2]=fmaf(xi3,xj2,acc[3][2]); acc[3][3]=fmaf(xi3,xj3,acc[3][3]);
        }
        if (tid < 64) cs += Xs[0][tid] + Xs[1][tid] + Xs[2][tid] + Xs[3][tid];
    }
    float* Gp = G + (size_t)bh * 4096;
    #pragma unroll
    for (int i = 0; i < 4; ++i)
        #pragma unroll
        for (int j = 0; j < 4; ++j)
            atomicAdd(&Gp[(i0 + i) * 64 + j0 + j], acc[i][j]);
    if (tid < 64) atomicAdd(&CS[bh * 64 + tid], cs);
}

// ---------------- per (st,b,h) scale = rsqrt(var(QK^T)+eps) ----------------
__global__ __launch_bounds__(256) void spatial_scale(
    const float* __restrict__ GQ, const float* __restrict__ GK,
    const float* __restrict__ SQm, const float* __restrict__ SKm, float* __restrict__ SVo)
{
    int st = blockIdx.y, bh = blockIdx.x, tid = threadIdx.x;
    const float* gq = GQ + (size_t)st*65536 + bh*4096;
    const float* gk = GK + bh*4096;
    double e2 = 0.0;
    for (int i = tid; i < 4096; i += 256)
        e2 += (double)gq[i] * (double)gk[i];
    double mm = 0.0;
    if (tid < 64) mm = (double)SQm[(size_t)st*1024 + bh*64 + tid] * (double)SKm[bh*64 + tid];
    #pragma unroll
    for (int m = 32; m; m >>= 1) { e2 += __shfl_xor(e2, m); mm += __shfl_xor(mm, m); }
    __shared__ double se[4], sm[4];
    int w = tid >> 6;
    if ((tid & 63) == 0) { se[w] = e2; sm[w] = mm; }
    __syncthreads();
    if (tid == 0) {
        double cnt = (double)NTOK * (double)TKV;
        double E2 = (se[0]+se[1]+se[2]+se[3]) / cnt;
        double M  = (sm[0]+sm[1]+sm[2]+sm[3]) / cnt;
        double var = E2 - M * M;
        SVo[st*16+bh] = (float)(1.0 / sqrt(var + 1e-5));
    }
}

// ---------------- MFMA flash attention: no-max softmax, bf16 P, XCD-grouped grid ----------------
// flat grid 768: xcd=g&7, loc=g>>3; n=loc&15, grp=loc>>4; sbh=xcd*6+grp; st=sbh/16, bh=sbh%16.
// All 16 n-tiles sharing one (st,bh)'s K/V land on the same XCD's L2.
__global__ __launch_bounds__(256) void flash_mfma(
    const ushort* __restrict__ Qhi, const ushort* __restrict__ Qlo,
    const ushort* __restrict__ Khi, const ushort* __restrict__ Klo,
    const ushort* __restrict__ VThi, const ushort* __restrict__ VTlo,
    const float* __restrict__ SV,
    ushort* __restrict__ Ohi, ushort* __restrict__ Olo)
{
    __shared__ ushort Kh[4096], Kl[4096], Vh[4096], Vl[4096], Ph[4096];
    const int g = blockIdx.x;
    const int xcd = g & 7, loc = g >> 3;
    const int sbh = xcd*6 + (loc >> 4);
    const int st = sbh >> 4, bh = sbh & 15;
    const int b = bh>>3, h = bh&7;
    const int n0 = (loc & 15) << 6;
    const int tid = threadIdx.x, wave = tid>>6, lane = tid&63;
    const int fr = lane&15, fq = lane>>4;
    const float sc = SV[st*16 + bh];
    const size_t qb = (size_t)st*1048576 + (size_t)(b*1024 + n0)*512 + h*64;
    bf16x8 qfh[2], qfl[2];
    {
        const ushort* qph = Qhi + qb + (size_t)(wave*16 + fr)*512;
        const ushort* qpl = Qlo + qb + (size_t)(wave*16 + fr)*512;
        #pragma unroll
        for (int ks=0; ks<2; ++ks) {
            qfh[ks] = ldsb8(qph + ks*32 + fq*8);
            qfl[ks] = ldsb8(qpl + ks*32 + fq*8);
        }
    }
    f32x4 accO[4]; float lsum[4];
    #pragma unroll
    for (int i=0;i<4;++i){ accO[i]=(f32x4){0.f,0.f,0.f,0.f}; lsum[i]=0.f; }
    const size_t kb = (size_t)(b*TKV)*512 + h*64;
    const size_t vb = (size_t)(h*64)*VSTRIDE + b*TKV;
    for (int t0=0; t0<TKV; t0+=64) {
        #pragma unroll
        for (int it=0; it<2; ++it) {
            int r  = (wave<<4) + (it<<3) + (lane>>3);
            int lb = ((wave<<4) + (it<<3)) << 6;
            int gck = ((lane&7) ^ (r&7)) << 3;
            size_t gk = kb + (size_t)(t0+r)*512 + gck;
            size_t gv = vb + (size_t)r*VSTRIDE + t0 + gck;
            async16(Khi+gk, &Kh[lb]);
            async16(Klo+gk, &Kl[lb]);
            async16(VThi+gv, &Vh[lb]);
            async16(VTlo+gv, &Vl[lb]);
        }
        __syncthreads();
        f32x4 s[4];
        #pragma unroll
        for (int i=0;i<4;++i) s[i]=(f32x4){0.f,0.f,0.f,0.f};
        __builtin_amdgcn_s_setprio(1);
        #pragma unroll
        for (int ks=0; ks<2; ++ks) {
            #pragma unroll
            for (int nf=0; nf<4; ++nf) {
                int r = nf*16+fr;
                int ko = (r<<6) + ((ks*32 + fq*8) ^ ((r&7)<<3));
                bf16x8 kh = ldsb8(&Kh[ko]), kl = ldsb8(&Kl[ko]);
                s[nf] = MFMA16(qfh[ks], kh, s[nf]);
                s[nf] = MFMA16(qfh[ks], kl, s[nf]);
                s[nf] = MFMA16(qfl[ks], kh, s[nf]);
            }
        }
        __builtin_amdgcn_s_setprio(0);
        #pragma unroll
        for (int reg=0; reg<4; ++reg) {
            int prow = fq*4+reg;
            float psum = 0.f;
            #pragma unroll
            for (int nf=0;nf<4;++nf){
                float p = __expf(sc * s[nf][reg]);
                psum += p;
                int pidx = (wave<<10) + (prow<<6) + ((nf*16+fr) ^ ((prow&7)<<3));
                Ph[pidx] = f2bf(p);
            }
            lsum[reg] += psum;
        }
        __builtin_amdgcn_s_setprio(1);
        #pragma unroll
        for (int ks=0; ks<2; ++ks) {
            int po = (wave<<10) + (fr<<6) + ((ks*32 + fq*8) ^ ((fr&7)<<3));
            bf16x8 ph = ldsb8(&Ph[po]);
            #pragma unroll
            for (int df=0; df<4; ++df) {
                int dd = df*16+fr;
                int vo = (dd<<6) + ((ks*32 + fq*8) ^ ((dd&7)<<3));
                bf16x8 vh = ldsb8(&Vh[vo]), vl = ldsb8(&Vl[vo]);
                accO[df] = MFMA16(ph, vh, accO[df]);
                accO[df] = MFMA16(ph, vl, accO[df]);
            }
        }
        __builtin_amdgcn_s_setprio(0);
        __syncthreads();
    }
    #pragma unroll
    for (int reg=0; reg<4; ++reg) {
        #pragma unroll
        for (int m=1; m<16; m<<=1) lsum[reg] += __shfl_xor(lsum[reg], m, 16);
        float inv = 1.f/lsum[reg];
        int row = n0 + wave*16 + fq*4 + reg;
        #pragma unroll
        for (int df=0; df<4; ++df) {
            float v = accO[df][reg]*inv;
            size_t o = (size_t)st*1048576 + (size_t)(b*1024+row)*512 + h*64 + df*16 + fr;
            ushort hh = f2bf(v);
            Ohi[o] = hh; Olo[o] = f2bf(v-bf2f(hh));
        }
    }
}

// ---------------- workspace layout (byte offsets) ----------------
constexpr size_t OFF_CH  = 0;           // 8 doubles
constexpr size_t OFF_GK  = 64;          // 65536 f32
constexpr size_t OFF_SK  = 262208;      // 1024 f32
constexpr size_t OFF_GQ  = 266304;      // 3*65536 f32
constexpr size_t OFF_SQM = 1052736;     // 3*1024 f32
constexpr size_t OFF_SV  = 1065024;     // 48 f32
constexpr size_t ZERO_BYTES = 1065024;
constexpr size_t S0 = 1065472;          // W8: 8 x 1 MB (hi 512KB + lo 512KB)
constexpr size_t S1 = S0 + 8388608;     // WC weights -> ATT f32 -> {QB hilo, Kb hilo}
constexpr size_t S2 = S1 + 28311552;    // embC hilo -> KVS hilo
constexpr size_t S3 = S2 + 12582912;    // emb123 hilo
constexpr size_t S4 = S3 + 12582912;    // QCt hilo -> SIMhi (spills into S5)
constexpr size_t S5 = S4 + 12582912;    // KCt hilo -> SIMlo tail -> CTX hilo
constexpr size_t S6 = S5 + 12582912;    // VC hilo -> VT hilo
// total = S6 + 12582912 = 100,680,192 bytes (~96 MB)

extern "C" void kernel_launch(void* const* d_in, const int* in_sizes, int n_in,
                              void* d_out, int out_size, void* d_ws, size_t ws_size,
                              hipStream_t stream)
{
    const float* emb[3] = {(const float*)d_in[0], (const float*)d_in[1], (const float*)d_in[2]};
    const float* embC = (const float*)d_in[3];
    const float* WqF[3] = {(const float*)d_in[4], (const float*)d_in[5], (const float*)d_in[6]};
    const float* WkF  = (const float*)d_in[7];
    const float* WvF  = (const float*)d_in[8];
    const float* WCF[3] = {(const float*)d_in[9], (const float*)d_in[10], (const float*)d_in[11]};
    const float* WoF[3] = {(const float*)d_in[12], (const float*)d_in[13], (const float*)d_in[14]};
    float* out = (float*)d_out;
    char* ws = (char*)d_ws;

    auto U16 = [&](size_t off)->ushort* { return (ushort*)(ws + off); };
    auto F32 = [&](size_t off)->float*  { return (float*)(ws + off); };

    double* CH = (double*)(ws + OFF_CH);
    float *GK = F32(OFF_GK), *SK = F32(OFF_SK), *GQ = F32(OFF_GQ), *SQm = F32(OFF_SQM), *SV = F32(OFF_SV);

    auto W8hi = [&](int i){ return U16(S0 + (size_t)i*1048576); };
    auto W8lo = [&](int i){ return U16(S0 + (size_t)i*1048576 + 524288); };
    auto WChi = [&](int i){ return U16(S1 + (size_t)i*9437184); };
    auto WClo = [&](int i){ return U16(S1 + (size_t)i*9437184 + 4718592); };
    ushort *embChi=U16(S2), *embClo=U16(S2+6291456);
    ushort *embhi=U16(S3), *emblo=U16(S3+6291456);
    ushort *QCthi=U16(S4), *QCtlo=U16(S4+6291456);
    ushort *KCthi=U16(S5), *KCtlo=U16(S5+6291456);
    ushort *VChi=U16(S6), *VClo=U16(S6+6291456);
    float  *ATT = F32(S1);
    ushort *SIMhi=U16(S4), *SIMlo=U16(S4+9437184);
    ushort *KVShi=U16(S2), *KVSlo=U16(S2+6291456);
    ushort *QBhi=U16(S1), *QBlo=U16(S1+6291456);
    ushort *Kbhi=U16(S1+12582912), *Kblo=U16(S1+12582912+6291456);
    ushort *VThi=U16(S6), *VTlo=U16(S6+6291456);
    ushort *CTXhi=U16(S5), *CTXlo=U16(S5+6291456);

    dim3 blk(256);
    (void)hipMemsetAsync(d_ws, 0, ZERO_BYTES, stream);

    // fp32 -> bf16 hi/lo conversions
    CvtJobs J;
    J.src[0]=embC;   J.hi[0]=embChi; J.lo[0]=embClo; J.n[0]=2048*KVCH;
    for (int s=0;s<3;++s){ J.src[1+s]=emb[s]; J.hi[1+s]=embhi+(size_t)s*1048576; J.lo[1+s]=emblo+(size_t)s*1048576; J.n[1+s]=2*NTOK*EDIM; }
    for (int s=0;s<3;++s){ J.src[4+s]=WqF[s]; J.hi[4+s]=W8hi(s); J.lo[4+s]=W8lo(s); J.n[4+s]=EDIM*EDIM; }
    J.src[7]=WkF; J.hi[7]=W8hi(3); J.lo[7]=W8lo(3); J.n[7]=EDIM*EDIM;
    J.src[8]=WvF; J.hi[8]=W8hi(4); J.lo[8]=W8lo(4); J.n[8]=EDIM*EDIM;
    for (int s=0;s<3;++s){ J.src[9+s]=WCF[s]; J.hi[9+s]=WChi(s); J.lo[9+s]=WClo(s); J.n[9+s]=KVCH*KVCH; }
    for (int s=0;s<3;++s){ J.src[12+s]=WoF[s]; J.hi[12+s]=W8hi(5+s); J.lo[12+s]=W8lo(5+s); J.n[12+s]=EDIM*EDIM; }
    cvt_hilo<<<dim3(3072, NCVT), blk, 0, stream>>>(J);

    GemmDesc Z{}; Z.zmod = 1;

    // L3: channel projections — QK transposed (z=w*2+b) + V natural (z=b)
    {
        GemmDesc dq = Z;
        dq.Ahi=embChi; dq.Alo=embClo; dq.Bhi=WChi(0); dq.Blo=WClo(0);
        dq.Cthi=QCthi; dq.Ctlo=QCtlo;
        dq.K=KVCH; dq.lda=KVCH; dq.ldb=KVCH; dq.ldct=NTOK;
        dq.zmod=2; dq.sA0=0; dq.sA1=(long)NTOK*KVCH; dq.sB0=4718592; dq.sB1=0;
        dq.sC0=6291456; dq.sC1=(long)KVCH*NTOK;
        GemmDesc dv = Z;
        dv.Ahi=embChi; dv.Alo=embClo; dv.Bhi=WChi(2); dv.Blo=WClo(2);
        dv.Chi=VChi; dv.Clo=VClo;
        dv.K=KVCH; dv.lda=KVCH; dv.ldb=KVCH; dv.ldc=KVCH;
        dv.sA0=(long)NTOK*KVCH; dv.sC0=(long)NTOK*KVCH;
        mgemmF<<<dim3(576), blk, 0, stream>>>(dq, dv, 384, 12, 8, 12, 8);
    }
    // L4: ATT[b] = QC^T KC (+ mean/var stats in epilogue)
    {
        GemmDesc da = Z;
        da.Ahi=QCthi; da.Alo=QCtlo; da.Bhi=KCthi; da.Blo=KCtlo;
        da.Cf=ATT; da.stats=CH;
        da.K=NTOK; da.lda=NTOK; da.ldb=NTOK; da.ldc=KVCH;
        da.sA0=(long)KVCH*NTOK; da.sB0=(long)KVCH*NTOK; da.sC0=(long)KVCH*KVCH;
        mgemmF<<<dim3(288), blk, 0, stream>>>(da, da, 288, 12, 12, 1, 1);
    }
    chan_softmax<<<dim3(1536,2), blk, 0, stream>>>(ATT, CH, SIMhi, SIMlo);
    // L6: KVS (z=b*3+j) + Q projections (z=stream)
    {
        GemmDesc dk = Z;
        dk.Ahi=VChi; dk.Alo=VClo; dk.Bhi=SIMhi; dk.Blo=SIMlo;
        dk.Chi=KVShi; dk.Clo=KVSlo;
        dk.K=KVCH; dk.lda=KVCH; dk.ldb=KVCH; dk.ldc=EDIM;
        dk.zmod=3; dk.sA0=(long)NTOK*KVCH; dk.sA1=0;
        dk.sB0=(long)KVCH*KVCH; dk.sB1=(long)EDIM*KVCH;
        dk.sC0=(long)TKV*EDIM; dk.sC1=(long)NTOK*EDIM;
        GemmDesc dqp = Z;
        dqp.Ahi=embhi; dqp.Alo=emblo; dqp.Bhi=W8hi(0); dqp.Blo=W8lo(0);
        dqp.Chi=QBhi; dqp.Clo=QBlo;
        dqp.K=EDIM; dqp.lda=EDIM; dqp.ldb=EDIM; dqp.ldc=EDIM;
        dqp.sA0=1048576; dqp.sB0=524288; dqp.sC0=1048576;
        mgemmF<<<dim3(384), blk, 0, stream>>>(dk, dqp, 192, 4, 8, 4, 16);
    }
    // L7: K projection (natural) + V projection (transposed -> VT directly)
    {
        GemmDesc dkp = Z;
        dkp.Ahi=KVShi; dkp.Alo=KVSlo; dkp.Bhi=W8hi(3); dkp.Blo=W8lo(3);
        dkp.Chi=Kbhi; dkp.Clo=Kblo;
        dkp.K=EDIM; dkp.lda=EDIM; dkp.ldb=EDIM; dkp.ldc=EDIM;
        GemmDesc dvp = Z;
        dvp.Ahi=KVShi; dvp.Alo=KVSlo; dvp.Bhi=W8hi(4); dvp.Blo=W8lo(4);
        dvp.Cthi=VThi; dvp.Ctlo=VTlo;
        dvp.K=EDIM; dvp.lda=EDIM; dvp.ldb=EDIM; dvp.ldct=VSTRIDE;
        mgemmF<<<dim3(384), blk, 0, stream>>>(dkp, dvp, 192, 4, 48, 4, 48);
    }
    gram4<<<dim3(16,8,4), blk, 0, stream>>>(Kbhi, Kblo, QBhi, QBlo, GK, SK, GQ, SQm);
    spatial_scale<<<dim3(16,3), blk, 0, stream>>>(GQ, GK, SQm, SK, SV);
    flash_mfma<<<dim3(768), blk, 0, stream>>>(QBhi, QBlo, Kbhi, Kblo, VThi, VTlo, SV, CTXhi, CTXlo);
    // L11: output projections
    {
        GemmDesc dop = Z;
        dop.Ahi=CTXhi; dop.Alo=CTXlo; dop.Bhi=W8hi(5); dop.Blo=W8lo(5);
        dop.Cf=out;
        dop.K=EDIM; dop.lda=EDIM; dop.ldb=EDIM; dop.ldc=EDIM;
        dop.sA0=1048576; dop.sB0=524288; dop.sC0=1048576;
        mgemmF<<<dim3(192), blk, 0, stream>>>(dop, dop, 192, 4, 16, 1, 1);
    }
}